// Round 1
// 201.163 us; speedup vs baseline: 1.0612x; 1.0612x over previous
//
#include <hip/hip_runtime.h>
#include <hip/hip_fp16.h>
#include <cstddef>

#define Bc   32
#define Nc   512
#define Mc   512
#define DFc  64
#define BIGC 1.0e10f
#define LOG2E_F 1.4426950408889634f
#define LN2_F   0.6931471805599453f
#define SQRT_LOG2E_F 1.2011224087864498f

typedef unsigned int uint32;
typedef _Float16 f16x8 __attribute__((ext_vector_type(8)));
typedef float    f32x4 __attribute__((ext_vector_type(4)));

__device__ __forceinline__ float dpp_shr1(float oldv, float src) {
    return __int_as_float(__builtin_amdgcn_update_dpp(
        __float_as_int(oldv), __float_as_int(src), 0x138, 0xf, 0xf, false));
}
__device__ __forceinline__ float dpp_shr1_nc(float src) {
    return __int_as_float(__builtin_amdgcn_mov_dpp(
        __float_as_int(src), 0x138, 0xf, 0xf, false));
}
__device__ __forceinline__ float rl(float v, int lane) {
    return __int_as_float(__builtin_amdgcn_readlane(__float_as_int(v), lane));
}

// Bit-trick softmin, log2 domain, minus 127 (bias pre-folded into Dsk).
// No clamps: v_cvt_u32_f32 saturates negative inputs to 0 (= exp underflow).
__device__ __forceinline__ float softmin3m(float a, float b, float c) {
    float mn = fminf(fminf(a, b), c);
    float mx = fmaxf(fmaxf(a, b), c);
    float md = __builtin_amdgcn_fmed3f(a, b, c);
    uint32 b1 = (uint32)fmaf(mn - mx, 8388608.0f, 1065353216.0f);
    uint32 b2 = (uint32)fmaf(mn - md, 8388608.0f, 1065353216.0f);
    float E = 1.0f + (__int_as_float(b1) + __int_as_float(b2));
    return fmaf((float)__float_as_uint(E), -1.1920929e-7f, mn);
}

// ---------------------------------------------------------------------------
// Kernel 1 (rewritten): MFMA distance computation.
//   S = Xs · Ys^T via v_mfma_f32_16x16x32_f16 (f32 accum), then
//   D = (||xs||^2 + 127) + ||ys||^2 - 2*S   (log2-domain scaled, bias folded).
// LDS layout: row-major [row][64] halves with rotation 8*(row&7) halves so
// per-lane fragment reads (row = l&15, k = 8*(l>>4)+e) are conflict-free
// ds_read_b128. Epilogue writes the same P[col*67 + rowpair] staging as r8;
// the skewed dwordx4 output stage is byte-identical to r8.
// ---------------------------------------------------------------------------
__global__ __launch_bounds__(256) void dist_kernel(
    const float* __restrict__ X, const float* __restrict__ Y,
    uint32* __restrict__ Dsk)
{
    __shared__ __align__(16) unsigned char SMEM[35840];
    unsigned short* XsH = (unsigned short*)SMEM;            // 16384 B
    unsigned short* YsH = (unsigned short*)(SMEM + 16384);  // 16384 B
    uint32* P  = (uint32*)SMEM;                             // 34816 B (aliases Xs/Ys)
    float* xx2 = (float*)(SMEM + 34816);                    // 512 B (survives P)
    float* yy2 = (float*)(SMEM + 35328);                    // 512 B

    const int b     = blockIdx.z;
    const int strip = blockIdx.y;
    const int J     = blockIdx.x;
    const int tid   = threadIdx.x;

    const float* Xg = X + ((size_t)b * Nc + strip * 128) * DFc;
    const float* Yg = Y + ((size_t)b * Mc + J * 128) * DFc;

    // ---- stage X: scale, convert to f16, rotated layout; f32 row norms ----
#pragma unroll
    for (int it = 0; it < 8; ++it) {
        int e4 = it * 256 + tid;
        int n = e4 >> 4, k4 = (e4 & 15) * 4;
        float4 v = ((const float4*)Xg)[e4];
        float sx = v.x * SQRT_LOG2E_F, sy = v.y * SQRT_LOG2E_F;
        float sz = v.z * SQRT_LOG2E_F, sw = v.w * SQRT_LOG2E_F;
        __half2 h01 = __floats2half2_rn(sx, sy);
        __half2 h23 = __floats2half2_rn(sz, sw);
        int ho = (k4 + 8 * (n & 7)) & 63;
        uint2 u; u.x = *(uint32*)&h01; u.y = *(uint32*)&h23;
        *(uint2*)&XsH[n * 64 + ho] = u;
        float p = sx * sx + sy * sy + sz * sz + sw * sw;
        p += __shfl_xor(p, 1);
        p += __shfl_xor(p, 2);
        p += __shfl_xor(p, 4);
        p += __shfl_xor(p, 8);
        if ((tid & 15) == 0) xx2[n] = p + 127.0f;   // fold the +127 bias here
    }
    // ---- stage Y ----
#pragma unroll
    for (int it = 0; it < 8; ++it) {
        int e4 = it * 256 + tid;
        int m = e4 >> 4, k4 = (e4 & 15) * 4;
        float4 v = ((const float4*)Yg)[e4];
        float sx = v.x * SQRT_LOG2E_F, sy = v.y * SQRT_LOG2E_F;
        float sz = v.z * SQRT_LOG2E_F, sw = v.w * SQRT_LOG2E_F;
        __half2 h01 = __floats2half2_rn(sx, sy);
        __half2 h23 = __floats2half2_rn(sz, sw);
        int ho = (k4 + 8 * (m & 7)) & 63;
        uint2 u; u.x = *(uint32*)&h01; u.y = *(uint32*)&h23;
        *(uint2*)&YsH[m * 64 + ho] = u;
        float p = sx * sx + sy * sy + sz * sz + sw * sw;
        p += __shfl_xor(p, 1);
        p += __shfl_xor(p, 2);
        p += __shfl_xor(p, 4);
        p += __shfl_xor(p, 8);
        if ((tid & 15) == 0) yy2[m] = p;
    }
    __syncthreads();

    const int l  = tid & 63;
    const int w  = tid >> 6;     // wave 0..3: rows [32w, 32w+32)
    const int lr = l & 15;       // fragment row/col
    const int lk = l >> 4;       // fragment k-group

    f32x4 acc[2][8];
#pragma unroll
    for (int rt = 0; rt < 2; ++rt)
#pragma unroll
        for (int ct = 0; ct < 8; ++ct) {
            f32x4 z = {0.f, 0.f, 0.f, 0.f};
            acc[rt][ct] = z;
        }

#pragma unroll
    for (int ks = 0; ks < 2; ++ks) {
        f16x8 af[2], bf[8];
#pragma unroll
        for (int rt = 0; rt < 2; ++rt) {
            int row = w * 32 + rt * 16 + lr;
            int ho = (ks * 32 + lk * 8 + 8 * (row & 7)) & 63;
            af[rt] = *(const f16x8*)&XsH[row * 64 + ho];
        }
#pragma unroll
        for (int ct = 0; ct < 8; ++ct) {
            int col = ct * 16 + lr;
            int ho = (ks * 32 + lk * 8 + 8 * (col & 7)) & 63;
            bf[ct] = *(const f16x8*)&YsH[col * 64 + ho];
        }
#pragma unroll
        for (int rt = 0; rt < 2; ++rt)
#pragma unroll
            for (int ct = 0; ct < 8; ++ct)
                acc[rt][ct] = __builtin_amdgcn_mfma_f32_16x16x32_f16(
                    af[rt], bf[ct], acc[rt][ct], 0, 0, 0);
    }
    __syncthreads();   // Xs/Ys dead; P may now overwrite them

    // ---- epilogue: D = xx2[row] + yy2[col] - 2*S, pack row pairs into P ----
    // C/D layout: col = l&15 (+16*ct), row = w*32 + rt*16 + 4*lk + reg.
#pragma unroll
    for (int rt = 0; rt < 2; ++rt) {
        int rbase = w * 32 + rt * 16 + 4 * lk;
        f32x4 xr = *(const f32x4*)&xx2[rbase];
        int p0 = rbase >> 1;   // row-pair index (= w*16 + rt*8 + 2*lk)
#pragma unroll
        for (int ct = 0; ct < 8; ++ct) {
            int c = ct * 16 + lr;
            float yv = yy2[c];
            f32x4 a = acc[rt][ct];
            float d0 = xr[0] + yv - 2.0f * a[0];
            float d1 = xr[1] + yv - 2.0f * a[1];
            float d2 = xr[2] + yv - 2.0f * a[2];
            float d3 = xr[3] + yv - 2.0f * a[3];
            __half2 h0 = __floats2half2_rn(d0, d1);
            __half2 h1 = __floats2half2_rn(d2, d3);
            P[c * 67 + p0]     = *(uint32*)&h0;
            P[c * 67 + p0 + 1] = *(uint32*)&h1;
        }
    }
    __syncthreads();

    // ---- output stage: skewed dwordx4 layout (byte-identical to r8) ----
    const int q = tid >> 6;
    uint4* outt = (uint4*)Dsk + (((size_t)b * 4 + strip) * 4 + J) * 4096;
    const uint32* Pl = P + l;
#pragma unroll
    for (int gi = 0; gi < 16; ++gi) {
        int g = q + 4 * gi;
        int ka = 4 * g - 2 * l;
        int c0 = min(max(ka,     0), 127);
        int c1 = min(max(ka + 1, 0), 127);
        int c2 = min(max(ka + 2, 0), 127);
        int c3 = min(max(ka + 3, 0), 127);
        uint32 p0 = Pl[c0 * 67];
        uint32 p1 = Pl[c1 * 67];
        uint32 p2 = Pl[c2 * 67];
        uint32 p3 = Pl[c3 * 67];
        uint4 v;
        v.x = (p0 & 0xffffu) | (p1 << 16);
        v.y = (p0 >> 16)     | (p1 & 0xffff0000u);
        v.z = (p2 & 0xffffu) | (p3 << 16);
        v.w = (p2 >> 16)     | (p3 & 0xffff0000u);
        outt[g * 64 + l] = v;
    }
}

// ---------------------------------------------------------------------------
// Kernel 2: single-pipeline 2-col superstep scan (r8 structure) with the
// issue-law trims: scalar (SALU-branch) output capture, clamp-free softmin,
// uniform-base global prefetch addressing. 4 waves (1/SIMD), 32 blocks.
// UNCHANGED this round.
// ---------------------------------------------------------------------------
#define SSTEP(T, dAw, dBw, PH1)                                            \
  {                                                                        \
    float2 fA = __half22float2(*(const __half2*)&(dAw));                   \
    float2 fB = __half22float2(*(const __half2*)&(dBw));                   \
    float u1, u2;                                                          \
    if (PH1) {                                                             \
      u1 = dpp_shr1(rl(Fodd, (T) - 1), pub1);                              \
      u2 = dpp_shr1(rl(Fev,  (T) - 1), curB);                              \
    } else {                                                               \
      u1 = dpp_shr1_nc(pub1);                                              \
      u2 = dpp_shr1_nc(curB);                                              \
    }                                                                      \
    float A1 = softmin3m(diagA, u1, curA) + fA.x;                          \
    float A2 = softmin3m(u1, u2, A1) + fA.y;                               \
    float B1 = softmin3m(curA, A1, curB) + fB.x;                           \
    float B2 = softmin3m(A1, A2, B1) + fB.y;                               \
    if ((T) == scap)                                                       \
      capv = useB ? (useC2 ? B2 : B1) : (useC2 ? A2 : A1);                 \
    bool act = (PH1) ? (l < (T)) : (l >= (T) - 64);                        \
    pub1  = act ? B1 : curB;   /* reads curB BEFORE update */              \
    curA  = act ? A2 : curA;                                               \
    curB  = act ? B2 : curB;                                               \
    diagA = u2;                                                            \
    if (!(PH1)) { wbase[2 * (T) - 127] = B1; wbase[2 * (T) - 126] = B2; }  \
  }

__global__ __launch_bounds__(256) void scan_kernel(
    const uint32* __restrict__ Dsk,
    const int* __restrict__ X_len, const int* __restrict__ Y_len,
    float* __restrict__ out)
{
    __shared__ __align__(16) float Frow[4][520];
    __shared__ float dumpArr[136];

    const int tid = threadIdx.x;
    const int l  = tid & 63;
    const int wl = __builtin_amdgcn_readfirstlane(tid >> 6);  // strip 0..3
    const int bb = blockIdx.x;

    const int xl = X_len[bb], yl = Y_len[bb];
    const int wxl  = (xl - 1) >> 7;           // capture strip
    const int iw   = (xl - 1) & 127;
    const int lcap = iw >> 1;                 // capture lane
    const int useB = iw & 1;                  // row parity (A/B)
    const int Jcap = (yl - 1) >> 7;           // capture tile (128-col)
    const int ycol = yl - (Jcap << 7);        // 1..128
    const int useC2 = 1 - (ycol & 1);         // even rel-col -> second cell
    const int tcap = ((ycol + 1) >> 1) + lcap;   // in [1,127]
    const int kmax = wxl + Jcap;              // <= 6

    const bool is63 = (l == 63);

    if (l == 0) Frow[wl][0] = BIGC;           // col-0 border for f0 at J=0
    __syncthreads();

    float curA = BIGC, curB = BIGC, pub1 = BIGC;
    float diagA = BIGC;
    float capv = 0.0f;

    for (int k = 0; k <= kmax; ++k) {
        int J = k - wl;
        if (wl <= wxl && 0 <= J && J <= Jcap) {
            const int j0 = J << 7;
            float Fodd, Fev, f0;
            if (wl > 0) {
                Fodd = Frow[wl - 1][j0 + 1 + 2 * l];   // odd rel-cols 1..127
                Fev  = Frow[wl - 1][j0 + 2 + 2 * l];   // even rel-cols 2..128
                f0   = Frow[wl - 1][j0];               // diag seed col j0
            } else {
                Fodd = BIGC; Fev = BIGC;
                f0 = (J == 0) ? 0.0f : BIGC;           // R[0][0] = 0
            }
            diagA = (l == 0) ? f0 : diagA;

            // uniform byte base + per-lane 16B offset: keeps prefetch
            // address bumps on SALU (imm/uniform), off the VALU budget.
            const char* tb = (const char*)Dsk +
                (((((size_t)bb * 4 + wl) * 4) + J) * 4096) * 16;
            const int voff = l * 16;
            const int scap = (wl == wxl && J == Jcap) ? tcap : -1000;
            float* wbase = is63 ? (&Frow[wl][j0]) : (dumpArr + 4);

            uint4 dreg[4];
            dreg[0] = *(const uint4*)(tb + voff);
            dreg[1] = *(const uint4*)(tb + voff + 1024);
            dreg[2] = *(const uint4*)(tb + voff + 2048);
            dreg[3] = *(const uint4*)(tb + voff + 3072);

            // ---- phase 1: g 0..31 (t = 1..64): lane0 inject, no stores ----
#pragma unroll 1
            for (int m = 0; m < 8; ++m) {
#pragma unroll
                for (int q = 0; q < 4; ++q) {
                    const int g = m * 4 + q;
                    uint4 dc = dreg[q];
                    dreg[q] = *(const uint4*)(tb + voff + (g + 4) * 1024);
                    SSTEP(2 * g + 1, dc.x, dc.y, true)
                    SSTEP(2 * g + 2, dc.z, dc.w, true)
                }
            }
            // t=64 boundary publish: lane63 (just activated) cols 1,2
            wbase[1] = pub1;
            wbase[2] = curB;

            // ---- phase 2: g 32..59 (t = 65..120): no inject, store pair ----
#pragma unroll 1
            for (int m = 8; m < 15; ++m) {
#pragma unroll
                for (int q = 0; q < 4; ++q) {
                    const int g = m * 4 + q;
                    uint4 dc = dreg[q];
                    dreg[q] = *(const uint4*)(tb + voff + (g + 4) * 1024);
                    SSTEP(2 * g + 1, dc.x, dc.y, false)
                    SSTEP(2 * g + 2, dc.z, dc.w, false)
                }
            }
            // ---- peel: g 60..63 (t = 121..127; t=128 skipped) ----
#pragma unroll
            for (int q = 0; q < 4; ++q) {
                const int g = 60 + q;
                uint4 dc = dreg[q];
                SSTEP(2 * g + 1, dc.x, dc.y, false)
                if (g < 63) { SSTEP(2 * g + 2, dc.z, dc.w, false) }
            }
        }
        __syncthreads();
    }

    if (wl == wxl) {
        float o = rl(capv, lcap);
        if (l == 0) out[bb] = o * LN2_F;
    }
}

extern "C" void kernel_launch(void* const* d_in, const int* in_sizes, int n_in,
                              void* d_out, int out_size, void* d_ws, size_t ws_size,
                              hipStream_t stream)
{
    const float* X  = (const float*)d_in[0];
    const float* Y  = (const float*)d_in[1];
    const int*   xl = (const int*)d_in[2];
    const int*   yl = (const int*)d_in[3];
    float* out = (float*)d_out;
    uint32* Dsk = (uint32*)d_ws;   // 32 b * 4 strips * 4 J * 64 KB = 32 MB

    dist_kernel<<<dim3(4, 4, Bc), 256, 0, stream>>>(X, Y, Dsk);
    scan_kernel<<<Bc, 256, 0, stream>>>(Dsk, xl, yl, out);
}

// Round 2
// 199.512 us; speedup vs baseline: 1.0700x; 1.0083x over previous
//
#include <hip/hip_runtime.h>
#include <hip/hip_fp16.h>
#include <cstddef>

#define Bc   32
#define Nc   512
#define Mc   512
#define DFc  64
#define BIGC 1.0e10f
#define LOG2E_F 1.4426950408889634f
#define LN2_F   0.6931471805599453f
#define SQRT_LOG2E_F 1.2011224087864498f

typedef unsigned int uint32;
typedef _Float16 f16x8 __attribute__((ext_vector_type(8)));
typedef float    f32x4 __attribute__((ext_vector_type(4)));

__device__ __forceinline__ float dpp_shr1(float oldv, float src) {
    return __int_as_float(__builtin_amdgcn_update_dpp(
        __float_as_int(oldv), __float_as_int(src), 0x138, 0xf, 0xf, false));
}
__device__ __forceinline__ float dpp_shr1_nc(float src) {
    return __int_as_float(__builtin_amdgcn_mov_dpp(
        __float_as_int(src), 0x138, 0xf, 0xf, false));
}
__device__ __forceinline__ float rl(float v, int lane) {
    return __int_as_float(__builtin_amdgcn_readlane(__float_as_int(v), lane));
}

// Bit-trick softmin, log2 domain, minus 127 (bias pre-folded into Dsk).
__device__ __forceinline__ float softmin3m(float a, float b, float c) {
    float mn = fminf(fminf(a, b), c);
    float mx = fmaxf(fmaxf(a, b), c);
    float md = __builtin_amdgcn_fmed3f(a, b, c);
    uint32 b1 = (uint32)fmaf(mn - mx, 8388608.0f, 1065353216.0f);
    uint32 b2 = (uint32)fmaf(mn - md, 8388608.0f, 1065353216.0f);
    float E = 1.0f + (__int_as_float(b1) + __int_as_float(b2));
    return fmaf((float)__float_as_uint(E), -1.1920929e-7f, mn);
}

// ---------------------------------------------------------------------------
// Kernel 1 (unchanged from round 1): MFMA distance computation.
// ---------------------------------------------------------------------------
__global__ __launch_bounds__(256) void dist_kernel(
    const float* __restrict__ X, const float* __restrict__ Y,
    uint32* __restrict__ Dsk)
{
    __shared__ __align__(16) unsigned char SMEM[35840];
    unsigned short* XsH = (unsigned short*)SMEM;            // 16384 B
    unsigned short* YsH = (unsigned short*)(SMEM + 16384);  // 16384 B
    uint32* P  = (uint32*)SMEM;                             // 34816 B (aliases Xs/Ys)
    float* xx2 = (float*)(SMEM + 34816);                    // 512 B (survives P)
    float* yy2 = (float*)(SMEM + 35328);                    // 512 B

    const int b     = blockIdx.z;
    const int strip = blockIdx.y;
    const int J     = blockIdx.x;
    const int tid   = threadIdx.x;

    const float* Xg = X + ((size_t)b * Nc + strip * 128) * DFc;
    const float* Yg = Y + ((size_t)b * Mc + J * 128) * DFc;

#pragma unroll
    for (int it = 0; it < 8; ++it) {
        int e4 = it * 256 + tid;
        int n = e4 >> 4, k4 = (e4 & 15) * 4;
        float4 v = ((const float4*)Xg)[e4];
        float sx = v.x * SQRT_LOG2E_F, sy = v.y * SQRT_LOG2E_F;
        float sz = v.z * SQRT_LOG2E_F, sw = v.w * SQRT_LOG2E_F;
        __half2 h01 = __floats2half2_rn(sx, sy);
        __half2 h23 = __floats2half2_rn(sz, sw);
        int ho = (k4 + 8 * (n & 7)) & 63;
        uint2 u; u.x = *(uint32*)&h01; u.y = *(uint32*)&h23;
        *(uint2*)&XsH[n * 64 + ho] = u;
        float p = sx * sx + sy * sy + sz * sz + sw * sw;
        p += __shfl_xor(p, 1);
        p += __shfl_xor(p, 2);
        p += __shfl_xor(p, 4);
        p += __shfl_xor(p, 8);
        if ((tid & 15) == 0) xx2[n] = p + 127.0f;   // fold the +127 bias here
    }
#pragma unroll
    for (int it = 0; it < 8; ++it) {
        int e4 = it * 256 + tid;
        int m = e4 >> 4, k4 = (e4 & 15) * 4;
        float4 v = ((const float4*)Yg)[e4];
        float sx = v.x * SQRT_LOG2E_F, sy = v.y * SQRT_LOG2E_F;
        float sz = v.z * SQRT_LOG2E_F, sw = v.w * SQRT_LOG2E_F;
        __half2 h01 = __floats2half2_rn(sx, sy);
        __half2 h23 = __floats2half2_rn(sz, sw);
        int ho = (k4 + 8 * (m & 7)) & 63;
        uint2 u; u.x = *(uint32*)&h01; u.y = *(uint32*)&h23;
        *(uint2*)&YsH[m * 64 + ho] = u;
        float p = sx * sx + sy * sy + sz * sz + sw * sw;
        p += __shfl_xor(p, 1);
        p += __shfl_xor(p, 2);
        p += __shfl_xor(p, 4);
        p += __shfl_xor(p, 8);
        if ((tid & 15) == 0) yy2[m] = p;
    }
    __syncthreads();

    const int l  = tid & 63;
    const int w  = tid >> 6;     // wave 0..3: rows [32w, 32w+32)
    const int lr = l & 15;       // fragment row/col
    const int lk = l >> 4;       // fragment k-group

    f32x4 acc[2][8];
#pragma unroll
    for (int rt = 0; rt < 2; ++rt)
#pragma unroll
        for (int ct = 0; ct < 8; ++ct) {
            f32x4 z = {0.f, 0.f, 0.f, 0.f};
            acc[rt][ct] = z;
        }

#pragma unroll
    for (int ks = 0; ks < 2; ++ks) {
        f16x8 af[2], bf[8];
#pragma unroll
        for (int rt = 0; rt < 2; ++rt) {
            int row = w * 32 + rt * 16 + lr;
            int ho = (ks * 32 + lk * 8 + 8 * (row & 7)) & 63;
            af[rt] = *(const f16x8*)&XsH[row * 64 + ho];
        }
#pragma unroll
        for (int ct = 0; ct < 8; ++ct) {
            int col = ct * 16 + lr;
            int ho = (ks * 32 + lk * 8 + 8 * (col & 7)) & 63;
            bf[ct] = *(const f16x8*)&YsH[col * 64 + ho];
        }
#pragma unroll
        for (int rt = 0; rt < 2; ++rt)
#pragma unroll
            for (int ct = 0; ct < 8; ++ct)
                acc[rt][ct] = __builtin_amdgcn_mfma_f32_16x16x32_f16(
                    af[rt], bf[ct], acc[rt][ct], 0, 0, 0);
    }
    __syncthreads();   // Xs/Ys dead; P may now overwrite them

#pragma unroll
    for (int rt = 0; rt < 2; ++rt) {
        int rbase = w * 32 + rt * 16 + 4 * lk;
        f32x4 xr = *(const f32x4*)&xx2[rbase];
        int p0 = rbase >> 1;
#pragma unroll
        for (int ct = 0; ct < 8; ++ct) {
            int c = ct * 16 + lr;
            float yv = yy2[c];
            f32x4 a = acc[rt][ct];
            float d0 = xr[0] + yv - 2.0f * a[0];
            float d1 = xr[1] + yv - 2.0f * a[1];
            float d2 = xr[2] + yv - 2.0f * a[2];
            float d3 = xr[3] + yv - 2.0f * a[3];
            __half2 h0 = __floats2half2_rn(d0, d1);
            __half2 h1 = __floats2half2_rn(d2, d3);
            P[c * 67 + p0]     = *(uint32*)&h0;
            P[c * 67 + p0 + 1] = *(uint32*)&h1;
        }
    }
    __syncthreads();

    const int q = tid >> 6;
    uint4* outt = (uint4*)Dsk + (((size_t)b * 4 + strip) * 4 + J) * 4096;
    const uint32* Pl = P + l;
#pragma unroll
    for (int gi = 0; gi < 16; ++gi) {
        int g = q + 4 * gi;
        int ka = 4 * g - 2 * l;
        int c0 = min(max(ka,     0), 127);
        int c1 = min(max(ka + 1, 0), 127);
        int c2 = min(max(ka + 2, 0), 127);
        int c3 = min(max(ka + 3, 0), 127);
        uint32 p0 = Pl[c0 * 67];
        uint32 p1 = Pl[c1 * 67];
        uint32 p2 = Pl[c2 * 67];
        uint32 p3 = Pl[c3 * 67];
        uint4 v;
        v.x = (p0 & 0xffffu) | (p1 << 16);
        v.y = (p0 >> 16)     | (p1 & 0xffff0000u);
        v.z = (p2 & 0xffffu) | (p3 << 16);
        v.w = (p2 >> 16)     | (p3 & 0xffff0000u);
        outt[g * 64 + l] = v;
    }
}

// ---------------------------------------------------------------------------
// Kernel 2: 2-col superstep scan. This round: 8-deep no-copy prefetch ring
// (window ~16 SSTEPs > HBM latency), cross-tile prologue prefetch (next-J
// loads issued during current tile's peel; J=0 prologue hoisted before the
// k-loop) to kill the per-superstep cold-start VMEM stall.
// ---------------------------------------------------------------------------
#define SSTEP(T, dAw, dBw, PH1)                                            \
  {                                                                        \
    float2 fA = __half22float2(*(const __half2*)&(dAw));                   \
    float2 fB = __half22float2(*(const __half2*)&(dBw));                   \
    float u1, u2;                                                          \
    if (PH1) {                                                             \
      u1 = dpp_shr1(rl(Fodd, (T) - 1), pub1);                              \
      u2 = dpp_shr1(rl(Fev,  (T) - 1), curB);                              \
    } else {                                                               \
      u1 = dpp_shr1_nc(pub1);                                              \
      u2 = dpp_shr1_nc(curB);                                              \
    }                                                                      \
    float A1 = softmin3m(diagA, u1, curA) + fA.x;                          \
    float A2 = softmin3m(u1, u2, A1) + fA.y;                               \
    float B1 = softmin3m(curA, A1, curB) + fB.x;                           \
    float B2 = softmin3m(A1, A2, B1) + fB.y;                               \
    if ((T) == scap)                                                       \
      capv = useB ? (useC2 ? B2 : B1) : (useC2 ? A2 : A1);                 \
    bool act = (PH1) ? (l < (T)) : (l >= (T) - 64);                        \
    pub1  = act ? B1 : curB;   /* reads curB BEFORE update */              \
    curA  = act ? A2 : curA;                                               \
    curB  = act ? B2 : curB;                                               \
    diagA = u2;                                                            \
    if (!(PH1)) { wbase[2 * (T) - 127] = B1; wbase[2 * (T) - 126] = B2; }  \
  }

__global__ __launch_bounds__(256) void scan_kernel(
    const uint32* __restrict__ Dsk,
    const int* __restrict__ X_len, const int* __restrict__ Y_len,
    float* __restrict__ out)
{
    __shared__ __align__(16) float Frow[4][520];
    __shared__ float dumpArr[136];

    const int tid = threadIdx.x;
    const int l  = tid & 63;
    const int wl = __builtin_amdgcn_readfirstlane(tid >> 6);  // strip 0..3
    const int bb = blockIdx.x;

    const int xl = X_len[bb], yl = Y_len[bb];
    const int wxl  = (xl - 1) >> 7;           // capture strip
    const int iw   = (xl - 1) & 127;
    const int lcap = iw >> 1;                 // capture lane
    const int useB = iw & 1;                  // row parity (A/B)
    const int Jcap = (yl - 1) >> 7;           // capture tile (128-col)
    const int ycol = yl - (Jcap << 7);        // 1..128
    const int useC2 = 1 - (ycol & 1);         // even rel-col -> second cell
    const int tcap = ((ycol + 1) >> 1) + lcap;   // in [1,127]
    const int kmax = wxl + Jcap;              // <= 6

    const bool is63 = (l == 63);
    const int voff = l * 16;

    // wave-uniform byte base for this strip's tiles (J advances by 65536 B)
    const char* tbw = (const char*)Dsk +
        ((((size_t)bb * 4 + wl) * 4) * 4096) * 16;

    if (l == 0) Frow[wl][0] = BIGC;           // col-0 border for f0 at J=0
    __syncthreads();

    float curA = BIGC, curB = BIGC, pub1 = BIGC;
    float diagA = BIGC;
    float capv = 0.0f;

    // prologue prefetch for tile J=0 (only waves that will ever be active)
    uint4 dreg[8];
    if (wl <= wxl) {
#pragma unroll
        for (int q = 0; q < 8; ++q)
            dreg[q] = *(const uint4*)(tbw + voff + q * 1024);
    }

    for (int k = 0; k <= kmax; ++k) {
        int J = k - wl;
        if (wl <= wxl && 0 <= J && J <= Jcap) {
            const int j0 = J << 7;
            float Fodd, Fev, f0;
            if (wl > 0) {
                Fodd = Frow[wl - 1][j0 + 1 + 2 * l];   // odd rel-cols 1..127
                Fev  = Frow[wl - 1][j0 + 2 + 2 * l];   // even rel-cols 2..128
                f0   = Frow[wl - 1][j0];               // diag seed col j0
            } else {
                Fodd = BIGC; Fev = BIGC;
                f0 = (J == 0) ? 0.0f : BIGC;           // R[0][0] = 0
            }
            diagA = (l == 0) ? f0 : diagA;

            const char* tb = tbw + (size_t)J * 65536;
            const int scap = (wl == wxl && J == Jcap) ? tcap : -1000;
            float* wbase = is63 ? (&Frow[wl][j0]) : (dumpArr + 4);
            const bool nextJ = (J < Jcap);

            // ---- phase 1: g 0..31 (t = 1..64): lane0 inject, no stores ----
#pragma unroll 1
            for (int m = 0; m < 4; ++m) {
#pragma unroll
                for (int q = 0; q < 8; ++q) {
                    const int g = m * 8 + q;
                    uint4 dc = dreg[q];
                    SSTEP(2 * g + 1, dc.x, dc.y, true)
                    SSTEP(2 * g + 2, dc.z, dc.w, true)
                    dreg[q] = *(const uint4*)(tb + voff + (g + 8) * 1024);
                }
            }
            // t=64 boundary publish: lane63 (just activated) cols 1,2
            wbase[1] = pub1;
            wbase[2] = curB;

            // ---- phase 2: g 32..55 (t = 65..112): no inject, store pair ----
#pragma unroll 1
            for (int m = 4; m < 7; ++m) {
#pragma unroll
                for (int q = 0; q < 8; ++q) {
                    const int g = m * 8 + q;
                    uint4 dc = dreg[q];
                    SSTEP(2 * g + 1, dc.x, dc.y, false)
                    SSTEP(2 * g + 2, dc.z, dc.w, false)
                    dreg[q] = *(const uint4*)(tb + voff + (g + 8) * 1024);
                }
            }
            // ---- peel: g 56..63 (t = 113..127; t=128 skipped).
            //      Interleave prologue prefetch for tile J+1. ----
#pragma unroll
            for (int q = 0; q < 8; ++q) {
                const int g = 56 + q;
                uint4 dc = dreg[q];
                SSTEP(2 * g + 1, dc.x, dc.y, false)
                if (g < 63) { SSTEP(2 * g + 2, dc.z, dc.w, false) }
                if (nextJ)
                    dreg[q] = *(const uint4*)(tb + 65536 + voff + q * 1024);
            }
        }
        __syncthreads();
    }

    if (wl == wxl) {
        float o = rl(capv, lcap);
        if (l == 0) out[bb] = o * LN2_F;
    }
}

extern "C" void kernel_launch(void* const* d_in, const int* in_sizes, int n_in,
                              void* d_out, int out_size, void* d_ws, size_t ws_size,
                              hipStream_t stream)
{
    const float* X  = (const float*)d_in[0];
    const float* Y  = (const float*)d_in[1];
    const int*   xl = (const int*)d_in[2];
    const int*   yl = (const int*)d_in[3];
    float* out = (float*)d_out;
    uint32* Dsk = (uint32*)d_ws;   // 32 b * 4 strips * 4 J * 64 KB = 32 MB

    dist_kernel<<<dim3(4, 4, Bc), 256, 0, stream>>>(X, Y, Dsk);
    scan_kernel<<<Bc, 256, 0, stream>>>(Dsk, xl, yl, out);
}